// Round 3
// baseline (530.275 us; speedup 1.0000x reference)
//
#include <hip/hip_runtime.h>
#include <math.h>

// ---- problem dims ----
#define BB   16
#define SS   8
#define TKK  400
#define HH   256
#define EE   128
#define VV   50000
#define OOVV 50
#define HH2  512
#define STK  (SS*TKK)     // 3200
#define VOO  (VV+OOVV)    // 50050

// ---- workspace offsets (floats) ----
#define OFF_X     0        // B*E      = 2048
#define OFF_ST    2048     // B*H2     = 8192   s_t_hat = [h,c]
#define OFF_SD    10240    // B*H2     = 8192  (bias-inited in k_pre, atomic accum)
#define OFF_WD    18432    // B*H2     = 8192  (bias-inited in k_pre, atomic accum)
#define OFF_SCSEC 26752    // B*S      = 128
#define OFF_SCW   26880    // B*S*TK   = 51200
#define OFF_CT    78080    // B*H2     = 8192  (zeroed in k_pre, atomic accum)
#define OFF_OUT1  86272    // B*H      = 4096
#define OFF_PGEN  90368    // B        = 16
#define OFF_PSUM  93520    // 16*391   = 6256, layout [b][blk]
#define OFF_BT    113040   // 512*512 bf16 (512KB), layout [round][col*4 + swz(kg)][8]

// ---- output offsets (floats) ----
#define O_FD   0
#define O_H    800800
#define O_C    804896
#define O_CT   808992
#define O_ATTN 817184
#define O_PGEN 868384
#define O_COV  868400

#define NLB 391            // logits blocks (128 cols each)
#define GEMM_NB 800

typedef __attribute__((ext_vector_type(8))) short bf16x8;
typedef __attribute__((ext_vector_type(4))) float f32x4;

__device__ __forceinline__ float sigm(float x){ return 1.0f/(1.0f+expf(-x)); }

__device__ __forceinline__ unsigned short f2b(float f){
  unsigned int u = __float_as_uint(f);
  unsigned int r = (u + 0x7fffu + ((u >> 16) & 1u)) >> 16;
  return (unsigned short)r;
}

// fast tanh: (e^2x - 1) * rcp(e^2x + 1), clamped.  abs err ~2e-7.
__device__ __forceinline__ float tanhfast(float x){
  float cx = fminf(9.0f, fmaxf(-9.0f, x));
  float t = __expf(2.0f*cx);
  return (t - 1.0f) * __builtin_amdgcn_rcpf(t + 1.0f);
}

__device__ __forceinline__ float wave_sum(float v){
  #pragma unroll
  for(int o=32;o>0;o>>=1) v += __shfl_xor(v,o);
  return v;
}
__device__ __forceinline__ float wave_max(float v){
  #pragma unroll
  for(int o=32;o>0;o>>=1) v = fmaxf(v,__shfl_xor(v,o));
  return v;
}

// async global->LDS, 16B per lane. LDS dest = wave-uniform base + lane*16.
__device__ __forceinline__ void glds16(const void* g, void* l){
  __builtin_amdgcn_global_load_lds((const __attribute__((address_space(1))) void*)g,
                                   (__attribute__((address_space(3))) void*)l, 16, 0, 0);
}

__device__ __forceinline__ bf16x8 cvt8(float4 a, float4 b){
  union{ bf16x8 v; unsigned short u[8]; } t;
  t.u[0]=f2b(a.x); t.u[1]=f2b(a.y); t.u[2]=f2b(a.z); t.u[3]=f2b(a.w);
  t.u[4]=f2b(b.x); t.u[5]=f2b(b.y); t.u[6]=f2b(b.z); t.u[7]=f2b(b.w);
  return t.v;
}

// ------------------------------------------------------------------
// k_pre: blocks 0..63  transpose Whw -> Btg bf16 (pre-swizzled round images)
//        blocks 64..79 x = [c_t_1, emb[y]] @ W_xc + b_xc
//        block  80     zero CT; init SD/WD with biases (k_proj accumulates)
// grid 81 x 256
__global__ void k_pre(const float* __restrict__ Whw, unsigned short* __restrict__ Btg,
                      const int* __restrict__ y, const float* __restrict__ ct1,
                      const float* __restrict__ emb, const float* __restrict__ Wxc,
                      const float* __restrict__ bxc, const float* __restrict__ bdsec,
                      const float* __restrict__ bdw, float* __restrict__ ws){
  __shared__ float sm[10440];
  int bi = blockIdx.x, tid = threadIdx.x;
  if(bi < 64){
    int n0 = (bi & 7)*64, k0 = (bi >> 3)*64;
    int tx = tid & 63, ty = tid >> 6;  // ty 0..3
    #pragma unroll
    for(int it=0; it<16; it++){
      int kk = it*4 + ty;
      sm[kk*65 + tx] = Whw[(size_t)(k0+kk)*HH2 + n0 + tx];
    }
    __syncthreads();
    #pragma unroll
    for(int it=0; it<2; it++){
      int kgl = it*4 + ty;            // 0..7
      int kgG = (k0 >> 3) + kgl;
      int rnd = kgG >> 2, kg = kgG & 3;
      int col = n0 + tx;
      union{ bf16x8 v; unsigned short u[8]; } t;
      #pragma unroll
      for(int j=0;j<8;j++) t.u[j] = f2b(sm[(kgl*8+j)*65 + tx]);
      *(bf16x8*)&Btg[(size_t)rnd*16384 + (size_t)(col*4 + (kg ^ ((col>>1)&3)))*8] = t.v;
    }
  } else if(bi < 80){
    float* cat = sm;                  // [b][640]
    float* red = sm + 10240;          // 128
    for(int f=tid; f<BB*640; f+=256){
      int b = f/640, r = f - b*640;
      cat[f] = (r < HH2) ? ct1[b*HH2 + r] : emb[(size_t)y[b]*EE + (r-HH2)];
    }
    __syncthreads();
    int c = (bi-64)*8 + (tid & 7);
    int b = (tid >> 3) & 15;
    int kh = tid >> 7;                // 0..1
    float acc = 0.0f;
    const float* a = &cat[b*640];
    for(int k=kh*320; k<kh*320+320; k++) acc += a[k]*Wxc[k*EE + c];
    if(kh==1) red[b*8 + (tid&7)] = acc;
    __syncthreads();
    if(kh==0) ws[OFF_X + b*EE + c] = acc + red[b*8 + (tid&7)] + bxc[c];
  } else {
    for(int f=tid; f<BB*HH2; f+=256){
      int c = f & (HH2-1);
      ws[OFF_CT + f] = 0.0f;
      ws[OFF_SD + f] = bdsec[c];
      ws[OFF_WD + f] = bdw[c];
    }
  }
}

// ------------------------------------------------------------------
// fused LSTM.  grid 64 x 256: block = 16 j-cols x 4 b, ksplit 4
__global__ void k_lstm(const float* __restrict__ h0, const float* __restrict__ c0,
                       const float* __restrict__ Wih, const float* __restrict__ bih,
                       const float* __restrict__ Whh, const float* __restrict__ bhh,
                       float* __restrict__ ws, float* __restrict__ out){
  __shared__ float xh[4*384];
  __shared__ float red[3*64*4];
  int tid = threadIdx.x;
  int jc = (blockIdx.x & 15)*16, bc = (blockIdx.x >> 4)*4;
  for(int f=tid; f<4*384; f+=256){
    int bl = f/384, r = f - bl*384;
    xh[f] = (r < EE) ? ws[OFF_X + (bc+bl)*EE + r] : h0[(bc+bl)*HH + (r-EE)];
  }
  __syncthreads();
  int jl = tid & 15, bl = (tid >> 4) & 3, kq = tid >> 6;
  int j = jc + jl, b = bc + bl;
  float a0=0.f, a1=0.f, a2=0.f, a3=0.f;
  const float* a = &xh[bl*384];
  for(int k=kq*96; k<kq*96+96; k++){
    float v = a[k];
    const float* w = (k < EE) ? &Wih[k*4*HH + j] : &Whh[(k-EE)*4*HH + j];
    a0 += v*w[0]; a1 += v*w[HH]; a2 += v*w[2*HH]; a3 += v*w[3*HH];
  }
  if(kq){
    float* r = &red[((kq-1)*64 + bl*16 + jl)*4];
    r[0]=a0; r[1]=a1; r[2]=a2; r[3]=a3;
  }
  __syncthreads();
  if(kq==0){
    #pragma unroll
    for(int p=0;p<3;p++){
      const float* r = &red[(p*64 + bl*16 + jl)*4];
      a0+=r[0]; a1+=r[1]; a2+=r[2]; a3+=r[3];
    }
    a0 += bih[j] + bhh[j];
    a1 += bih[j+HH] + bhh[j+HH];
    a2 += bih[j+2*HH] + bhh[j+2*HH];
    a3 += bih[j+3*HH] + bhh[j+3*HH];
    float c = sigm(a1)*c0[b*HH+j] + sigm(a0)*tanhf(a2);
    float h = sigm(a3)*tanhf(c);
    out[O_H + b*HH + j] = h;
    out[O_C + b*HH + j] = c;
    ws[OFF_ST + b*HH2 + j]      = h;
    ws[OFF_ST + b*HH2 + HH + j] = c;
  }
}

// ------------------------------------------------------------------
// sd/wd projections, coalesced.  grid 64 x 256.
// block = mi(2) x cb(2: 256-col half) x kq(16: 32-k chunk).
// threads <-> cols (coalesced W rows); st chunk in LDS; atomic accumulate
// into bias-inited SD/WD.
__global__ void k_proj(const float* __restrict__ Wdsec, const float* __restrict__ Wdw,
                       float* __restrict__ ws){
  __shared__ float st[BB*32];    // [b][kk]
  int tid = threadIdx.x;
  int mi = blockIdx.x >> 5;
  int cb = (blockIdx.x >> 4) & 1;
  int kq = blockIdx.x & 15;
  int k0 = kq*32;
  for(int f=tid; f<BB*32; f+=256){
    int b = f >> 5, kk = f & 31;
    st[f] = ws[OFF_ST + b*HH2 + k0 + kk];
  }
  __syncthreads();
  int c = cb*256 + tid;
  const float* Wm = (mi ? Wdw : Wdsec) + (size_t)k0*HH2 + c;
  float acc[BB];
  #pragma unroll
  for(int b=0;b<BB;b++) acc[b] = 0.0f;
  #pragma unroll 4
  for(int kk=0;kk<32;kk++){
    float wv = Wm[(size_t)kk*HH2];
    #pragma unroll
    for(int b=0;b<BB;b++) acc[b] += st[b*32 + kk]*wv;
  }
  int dst = mi ? OFF_WD : OFF_SD;
  #pragma unroll
  for(int b=0;b<BB;b++) atomicAdd(&ws[dst + b*HH2 + c], acc[b]);
}

// ------------------------------------------------------------------
// k_gemm6 blocks 0..799: 64 rows x 512 cols, K=512, BK=32.
//   Depth-2 counted-vmcnt pipeline:
//   - A(r+2) issued at TOP of round r into reg FIFO (2 slots), converted at
//     end of round r+1 -> ~2 rounds of latency tolerance. No A LDS traffic.
//   - B(r+2) via global_load_lds (pre-swizzled Btg) after BAR-A of round r,
//     consumed round r+2. Uniform s_waitcnt vmcnt(8) before BAR-B: leaves
//     L(r+2)x4 + G(r+2)x4 in flight, drains A(r+1)/B(r+1).
//   8 waves = 2 row-groups x 4 col-groups (wave tile 32x128): each col owned
//   by ONE wave -> B LDS replication 2x (was 4x); 8 ds_read_b128 + 16 MFMA.
// blocks 800..927: section attention (fp32-precise) -> SCSEC.
// grid 928 x 512, 64 KB LDS -> 2 blocks/CU (16 waves).
__global__ __launch_bounds__(512, 4) void k_gemm6(
        const float* __restrict__ A, const unsigned short* __restrict__ Btg,
        const float* __restrict__ Wcw, const float* __restrict__ vw,
        const float* __restrict__ cover,
        const float* __restrict__ sec, const float* __restrict__ Whsec,
        const float* __restrict__ vsec, float* __restrict__ ws){
  // shorts: Bs0[0..16383] Bs1[16384..32767]   (64 KB)
  __shared__ __align__(16) unsigned short smem[32768];
  int tid = threadIdx.x;
  if(blockIdx.x >= GEMM_NB){
    // ---- esec: one block per (b,s) row, precise fp32 ----
    float* row = (float*)smem;            // 512 floats
    float* red = row + HH2;               // 8
    int bi = blockIdx.x - GEMM_NB;        // 0..127
    int b = bi >> 3;
    if(tid < HH2) row[tid] = sec[(size_t)bi*HH2 + tid];
    __syncthreads();
    int col = tid;                        // 0..511
    float acc = 0.0f;
    #pragma unroll 8
    for(int k=0;k<HH2;k++) acc += row[k]*Whsec[k*HH2 + col];
    float val = tanhf(acc + ws[OFF_SD + b*HH2 + col]) * vsec[col];
    val = wave_sum(val);
    if((tid&63)==0) red[tid>>6] = val;
    __syncthreads();
    if(tid==0){
      float s = 0.0f;
      #pragma unroll
      for(int i=0;i<8;i++) s += red[i];
      ws[OFF_SCSEC + bi] = s;
    }
    return;
  }
  // ---- gemm ----
  int w = tid >> 6, lane = tid & 63, m = lane & 15, q = lane >> 4;
  int mk = (m >> 1) & 3, sw = q ^ mk;    // XOR-swizzle slot for kg reads
  int rg = w >> 2, cg = w & 3;           // 2 row-groups x 4 col-groups
  int row0 = blockIdx.x * 64;
  int b = blockIdx.x / 50;               // 50 blocks per batch

  // per-lane A fragment sources: rows rg*32+m and rg*32+16+m, k-slot q
  const float* a0p = &A[(size_t)(row0 + rg*32 + m)*HH2 + q*8];
  const float* a1p = a0p + (size_t)16*HH2;

  f32x4 acc0[8], acc1[8];
  #pragma unroll
  for(int j=0;j<8;j++){ acc0[j] = (f32x4){0.f,0.f,0.f,0.f}; acc1[j] = (f32x4){0.f,0.f,0.f,0.f}; }

  float4 pa[2][4];
  bf16x8 af0, af1;

  #define GLDSB(rr, buf) {                                                     \
    const unsigned short* bsrc_ = Btg + (size_t)(rr)*16384;                    \
    unsigned short* ldst_ = &smem[(buf)*16384];                                \
    _Pragma("unroll")                                                          \
    for(int i_=0;i_<4;i_++)                                                    \
      glds16(bsrc_ + i_*4096 + tid*8, ldst_ + i_*4096 + tid*8);                \
  }
  #define LOADA(rr, s) {                                                       \
    pa[s][0] = *(const float4*)(a0p + (rr)*32);                                \
    pa[s][1] = *(const float4*)(a0p + (rr)*32 + 4);                            \
    pa[s][2] = *(const float4*)(a1p + (rr)*32);                                \
    pa[s][3] = *(const float4*)(a1p + (rr)*32 + 4);                            \
  }

  // ---- prologue: FIFO = [B(0)x4, A(0)x4, A(1)x4, B(1)x4] ----
  GLDSB(0, 0);
  LOADA(0, 0);
  LOADA(1, 1);
  GLDSB(1, 1);
  asm volatile("s_waitcnt vmcnt(8)" ::: "memory");   // B(0),A(0) landed
  __builtin_amdgcn_sched_barrier(0);
  af0 = cvt8(pa[0][0], pa[0][1]);
  af1 = cvt8(pa[0][2], pa[0][3]);
  __builtin_amdgcn_s_barrier();                      // B(0) visible block-wide

  #pragma unroll
  for(int r=0; r<16; r++){
    if(r <= 13) LOADA(r+2, r&1);                     // A(r+2) early (2-rd flight)
    __builtin_amdgcn_s_setprio(1);
    #pragma unroll
    for(int cf=0; cf<8; cf++){
      int col = cg*128 + cf*16 + m;
      bf16x8 bv = *(const bf16x8*)&smem[(r&1)*16384 + ((size_t)col*4 + sw)*8];
      acc0[cf] = __builtin_amdgcn_mfma_f32_16x16x32_bf16(af0, bv, acc0[cf], 0,0,0);
      acc1[cf] = __builtin_amdgcn_mfma_f32_16x16x32_bf16(af1, bv, acc1[cf], 0,0,0);
    }
    __builtin_amdgcn_s_setprio(0);
    if(r <= 13){
      asm volatile("s_waitcnt lgkmcnt(0)" ::: "memory");  // my B reads retired
      __builtin_amdgcn_sched_barrier(0);
      __builtin_amdgcn_s_barrier();                  // BAR-A: buf[r&1] free
      GLDSB(r+2, r&1);                               // B(r+2)
    }
    if(r <= 14){
      if(r <= 13){ asm volatile("s_waitcnt vmcnt(8)" ::: "memory"); }
      else       { asm volatile("s_waitcnt vmcnt(0)" ::: "memory"); }
      __builtin_amdgcn_sched_barrier(0);
      af0 = cvt8(pa[(r+1)&1][0], pa[(r+1)&1][1]);    // A(r+1) in barrier shadow
      af1 = cvt8(pa[(r+1)&1][2], pa[(r+1)&1][3]);
      __builtin_amdgcn_s_barrier();                  // BAR-B: B(r+1) ready
    }
  }
  #undef GLDSB
  #undef LOADA

  // ---- epilogue: fold cols with tanh into per-row sums ----
  float cov0[4], cov1[4];
  #pragma unroll
  for(int r=0;r<4;r++){
    cov0[r] = cover[row0 + rg*32 + q*4 + r];
    cov1[r] = cover[row0 + rg*32 + 16 + q*4 + r];
  }
  float rs0[4] = {0,0,0,0}, rs1[4] = {0,0,0,0};
  #pragma unroll
  for(int j=0;j<8;j++){
    int col = cg*128 + j*16 + m;
    float wdv = ws[OFF_WD + b*HH2 + col];
    float wcv = Wcw[col], vwv = vw[col];
    #pragma unroll
    for(int r=0;r<4;r++){
      rs0[r] += tanhfast(acc0[j][r] + wdv + cov0[r]*wcv) * vwv;
      rs1[r] += tanhfast(acc1[j][r] + wdv + cov1[r]*wcv) * vwv;
    }
  }
  __syncthreads();                 // all waves past K-loop; smem reusable
  float* rbuf = (float*)smem;      // [cg][64 rows] = 256 floats
  #pragma unroll
  for(int r=0;r<4;r++){
    float v = rs0[r];
    v += __shfl_xor(v,1,16); v += __shfl_xor(v,2,16);
    v += __shfl_xor(v,4,16); v += __shfl_xor(v,8,16);
    if(m==0) rbuf[cg*64 + rg*32 + q*4 + r] = v;
    float u = rs1[r];
    u += __shfl_xor(u,1,16); u += __shfl_xor(u,2,16);
    u += __shfl_xor(u,4,16); u += __shfl_xor(u,8,16);
    if(m==0) rbuf[cg*64 + rg*32 + 16 + q*4 + r] = u;
  }
  __syncthreads();
  if(tid < 64)
    ws[OFF_SCW + row0 + tid] = rbuf[tid] + rbuf[64+tid] + rbuf[128+tid] + rbuf[192+tid];
}

// ------------------------------------------------------------------
// beta (inline) + attn softmax + mask + renorm + coverage out.  grid 16 x 1024
__global__ void k_attn(const float* __restrict__ mask, const float* __restrict__ cover,
                       float* __restrict__ ws, float* __restrict__ out){
  int b = blockIdx.x, tid = threadIdx.x;
  __shared__ float vals[STK];
  __shared__ float redm[16], reds[16];
  __shared__ float sc[SS];
  if(tid < SS) sc[tid] = ws[OFF_SCSEC + b*SS + tid];
  __syncthreads();
  float bm = -1e30f;
  #pragma unroll
  for(int s=0;s<SS;s++) bm = fmaxf(bm, sc[s]);
  float be[SS]; float bsum = 0.0f;
  #pragma unroll
  for(int s=0;s<SS;s++){ be[s] = expf(sc[s]-bm); bsum += be[s]; }
  #pragma unroll
  for(int s=0;s<SS;s++) be[s] /= bsum;
  int lane = tid & 63, w = tid >> 6;
  float m = -1e30f;
  for(int j=tid;j<STK;j+=1024){
    float v = be[j/TKK] * ws[OFF_SCW + b*STK + j];
    vals[j] = v; m = fmaxf(m, v);
  }
  m = wave_max(m);
  if(lane==0) redm[w] = m;
  __syncthreads();
  if(tid < 16){
    float t = redm[tid];
    #pragma unroll
    for(int o=8;o>0;o>>=1) t = fmaxf(t, __shfl_xor(t,o,16));
    if(tid==0) redm[0] = t;
  }
  __syncthreads();
  m = redm[0];
  float ssum = 0.0f;
  for(int j=tid;j<STK;j+=1024){
    float e = expf(vals[j]-m) * mask[b*STK + j];
    vals[j] = e; ssum += e;
  }
  ssum = wave_sum(ssum);
  if(lane==0) reds[w] = ssum;
  __syncthreads();
  if(tid < 16){
    float t = reds[tid];
    #pragma unroll
    for(int o=8;o>0;o>>=1) t += __shfl_xor(t,o,16);
    if(tid==0) reds[0] = t;
  }
  __syncthreads();
  float inv = 1.0f/reds[0];
  for(int j=tid;j<STK;j+=1024){
    float a = vals[j]*inv;
    out[O_ATTN + b*STK + j] = a;
    out[O_COV  + b*STK + j] = cover[b*STK + j] + a;
  }
}

// ------------------------------------------------------------------
// c_t = attn @ enc.  grid (50,16) x 256.  float4-coalesced, LDS pair-reduce,
// one atomic per col per block.
__global__ void k_ct(const float* __restrict__ enc, const float* __restrict__ out,
                     float* __restrict__ ws){
  int b = blockIdx.y, tid = threadIdx.x;
  __shared__ float a[64];
  __shared__ float part[512];
  int t0 = blockIdx.x*64;
  if(tid<64) a[tid] = out[O_ATTN + b*STK + t0 + tid];
  __syncthreads();
  int c4 = tid & 127, rh = tid >> 7;       // col-quad, row-half
  const float4* e4 = (const float4*)enc;
  size_t base = ((size_t)(b*STK + t0 + rh*32))*128 + c4;
  float4 acc = {0.f,0.f,0.f,0.f};
  #pragma unroll 8
  for(int rr=0; rr<32; rr++){
    float4 v = e4[base + (size_t)rr*128];
    float av = a[rh*32 + rr];
    acc.x += av*v.x; acc.y += av*v.y; acc.z += av*v.z; acc.w += av*v.w;
  }
  if(rh) *(float4*)&part[c4*4] = acc;
  __syncthreads();
  if(!rh){
    float4 o = *(const float4*)&part[c4*4];
    atomicAdd(&ws[OFF_CT + b*HH2 + c4*4 + 0], acc.x + o.x);
    atomicAdd(&ws[OFF_CT + b*HH2 + c4*4 + 1], acc.y + o.y);
    atomicAdd(&ws[OFF_CT + b*HH2 + c4*4 + 2], acc.z + o.z);
    atomicAdd(&ws[OFF_CT + b*HH2 + c4*4 + 3], acc.w + o.w);
  }
}

// ------------------------------------------------------------------
// out1: grid 65 x 256. blocks 0..63: 4 cols x 16 b, ksplit 4.
// block 64: p_gen + c_t output copy.
__global__ void k_out1(const float* __restrict__ Wp, const float* __restrict__ bp,
                       const float* __restrict__ Wo1, const float* __restrict__ bo1,
                       float* __restrict__ ws, float* __restrict__ out){
  __shared__ float cat[BB*768];   // 48 KB
  __shared__ float red[3*64];
  int tid = threadIdx.x;
  if(blockIdx.x == 64){
    int w = tid >> 6, lane = tid & 63;
    #pragma unroll
    for(int i=0;i<4;i++){
      int b = w*4 + i;
      float p = 0.0f;
      for(int k=lane;k<4*HH+EE;k+=64){
        float val = (k < HH2) ? ws[OFF_CT + b*HH2 + k]
                  : (k < 4*HH) ? ws[OFF_ST + b*HH2 + (k-HH2)]
                  : ws[OFF_X + b*EE + (k-4*HH)];
        p += val * Wp[k];
      }
      p = wave_sum(p);
      if(lane==0){
        float pg = sigm(p + bp[0]);
        ws[OFF_PGEN + b] = pg;
        out[O_PGEN + b]  = pg;
      }
    }
    for(int f=tid; f<BB*HH2; f+=256) out[O_CT + f] = ws[OFF_CT + f];
    return;
  }
  for(int f=tid; f<BB*768; f+=256){
    int b = f/768, r = f - b*768;
    cat[f] = (r < HH) ? ws[OFF_ST + b*HH2 + r] : ws[OFF_CT + b*HH2 + (r-HH)];
  }
  __syncthreads();
  int cl = tid & 3, bl = (tid >> 2) & 15, kq = tid >> 6;
  int c = blockIdx.x*4 + cl;
  float acc = 0.0f;
  const float* a = &cat[bl*768];
  for(int k=kq*192; k<kq*192+192; k++) acc += a[k]*Wo1[k*HH + c];
  if(kq) red[(kq-1)*64 + bl*4 + cl] = acc;
  __syncthreads();
  if(kq==0){
    acc += red[bl*4+cl] + red[64 + bl*4+cl] + red[128 + bl*4+cl];
    ws[OFF_OUT1 + bl*HH + c] = acc + bo1[c];
  }
}

// ------------------------------------------------------------------
// logits -> exp + per-block PSUM.  grid 391 x 256.
// Block = 128 cols x 16 b.  float4 W2 loads.
__global__ void k_logits(const float* __restrict__ W2, const float* __restrict__ b2,
                         float* __restrict__ ws, float* __restrict__ out){
  int tid = threadIdx.x;
  __shared__ float o1[BB*HH];        // 16 KB
  for(int i=tid;i<BB*HH/4;i+=256)
    ((float4*)o1)[i] = ((const float4*)&ws[OFF_OUT1])[i];
  __syncthreads();
  int cl = tid & 31, bq = tid >> 5;
  int c4 = blockIdx.x*128 + cl*4;
  bool ok = c4 < VV;
  int b0 = bq*2, b1 = b0+1;
  float4 acc0 = {0.f,0.f,0.f,0.f}, acc1 = {0.f,0.f,0.f,0.f};
  if(ok){
    const float* oa = &o1[b0*HH];
    const float* ob = &o1[b1*HH];
    #pragma unroll 4
    for(int k=0;k<HH;k++){
      float4 wv = *(const float4*)&W2[(size_t)k*VV + c4];
      float xa = oa[k], xb = ob[k];
      acc0.x += xa*wv.x; acc0.y += xa*wv.y; acc0.z += xa*wv.z; acc0.w += xa*wv.w;
      acc1.x += xb*wv.x; acc1.y += xb*wv.y; acc1.z += xb*wv.z; acc1.w += xb*wv.w;
    }
  }
  float bv[4] = {0,0,0,0};
  if(ok){ float4 t = *(const float4*)&b2[c4]; bv[0]=t.x; bv[1]=t.y; bv[2]=t.z; bv[3]=t.w; }
  float a0[4] = {acc0.x, acc0.y, acc0.z, acc0.w};
  float a1[4] = {acc1.x, acc1.y, acc1.z, acc1.w};
  float s0 = 0.0f, s1 = 0.0f;
  #pragma unroll
  for(int j=0;j<4;j++){
    float e0 = ok ? expf(a0[j]+bv[j]) : 0.0f;
    float e1 = ok ? expf(a1[j]+bv[j]) : 0.0f;
    if(ok){
      out[(size_t)b0*VOO + c4 + j] = e0;
      out[(size_t)b1*VOO + c4 + j] = e1;
    }
    s0 += e0; s1 += e1;
  }
  #pragma unroll
  for(int o=1;o<32;o<<=1){ s0 += __shfl_xor(s0,o,32); s1 += __shfl_xor(s1,o,32); }
  if(cl==0){
    ws[OFF_PSUM + b0*NLB + blockIdx.x] = s0;
    ws[OFF_PSUM + b1*NLB + blockIdx.x] = s1;
  }
}

// ------------------------------------------------------------------
// final_dist = p_gen * e / sum (v<V), extra_zeros tail.  grid (196,16) x 256
__global__ void k_final(const float* __restrict__ xz, float* __restrict__ ws,
                        float* __restrict__ out){
  int b = blockIdx.y;
  int v = blockIdx.x*256 + threadIdx.x;
  __shared__ float red[4];
  int lane = threadIdx.x & 63, w = threadIdx.x >> 6;
  float p = 0.0f;
  for(int i=threadIdx.x;i<NLB;i+=256) p += ws[OFF_PSUM + b*NLB + i];
  p = wave_sum(p);
  if(lane==0) red[w] = p;
  __syncthreads();
  float s = red[0]+red[1]+red[2]+red[3];
  float pg = ws[OFF_PGEN + b];
  if(v < VV)       out[(size_t)b*VOO + v] = pg * out[(size_t)b*VOO + v] / s;
  else if(v < VOO) out[(size_t)b*VOO + v] = xz[b*OOVV + (v-VV)];
}

// ------------------------------------------------------------------
// scatter-add (1-p_gen)*attn at extend-vocab indices.  grid (4,16) x 256
__global__ void k_scatter(const int* __restrict__ ebev, float* __restrict__ ws,
                          float* __restrict__ out){
  int b = blockIdx.y;
  float r = 1.0f - ws[OFF_PGEN + b];
  for(int j=blockIdx.x*256+threadIdx.x;j<STK;j+=1024){
    int idx = ebev[b*STK + j];
    atomicAdd(&out[(size_t)b*VOO + idx], r*out[O_ATTN + b*STK + j]);
  }
}

extern "C" void kernel_launch(void* const* d_in, const int* in_sizes, int n_in,
                              void* d_out, int out_size, void* d_ws, size_t ws_size,
                              hipStream_t stream){
  const int*   y     = (const int*)  d_in[0];
  const float* h0    = (const float*)d_in[1];
  const float* c0    = (const float*)d_in[2];
  const float* enc   = (const float*)d_in[3];
  const float* sec   = (const float*)d_in[4];
  const float* mask  = (const float*)d_in[5];
  const float* ct1   = (const float*)d_in[6];
  const float* xz    = (const float*)d_in[7];
  const int*   ebev  = (const int*)  d_in[8];
  const float* cover = (const float*)d_in[9];
  /* d_in[10] = gamma (unused by reference) */
  const float* emb   = (const float*)d_in[11];
  const float* Wxc   = (const float*)d_in[12];
  const float* bxc   = (const float*)d_in[13];
  const float* Wih   = (const float*)d_in[14];
  const float* bih   = (const float*)d_in[15];
  const float* Whh   = (const float*)d_in[16];
  const float* bhh   = (const float*)d_in[17];
  const float* Whsec = (const float*)d_in[18];
  const float* Wdsec = (const float*)d_in[19];
  const float* bdsec = (const float*)d_in[20];
  const float* vsec  = (const float*)d_in[21];
  const float* Whw   = (const float*)d_in[22];
  const float* Wcw   = (const float*)d_in[23];
  const float* Wdw   = (const float*)d_in[24];
  const float* bdw   = (const float*)d_in[25];
  const float* vw    = (const float*)d_in[26];
  const float* Wp    = (const float*)d_in[27];
  const float* bp    = (const float*)d_in[28];
  const float* Wo1   = (const float*)d_in[29];
  const float* bo1   = (const float*)d_in[30];
  const float* Wo2   = (const float*)d_in[31];
  const float* bo2   = (const float*)d_in[32];
  float* out = (float*)d_out;
  float* ws  = (float*)d_ws;
  unsigned short* Btg = (unsigned short*)(ws + OFF_BT);

  k_pre    <<<dim3(81),       dim3(256),  0, stream>>>(Whw, Btg, y, ct1, emb, Wxc, bxc, bdsec, bdw, ws);
  k_lstm   <<<dim3(64),       dim3(256),  0, stream>>>(h0, c0, Wih, bih, Whh, bhh, ws, out);
  k_proj   <<<dim3(64),       dim3(256),  0, stream>>>(Wdsec, Wdw, ws);
  k_gemm6  <<<dim3(928),      dim3(512),  0, stream>>>(enc, Btg, Wcw, vw, cover, sec, Whsec, vsec, ws);
  k_attn   <<<dim3(BB),       dim3(1024), 0, stream>>>(mask, cover, ws, out);
  k_ct     <<<dim3(50,BB),    dim3(256),  0, stream>>>(enc, out, ws);
  k_out1   <<<dim3(65),       dim3(256),  0, stream>>>(Wp, bp, Wo1, bo1, ws, out);
  k_logits <<<dim3(NLB),      dim3(256),  0, stream>>>(Wo2, bo2, ws, out);
  k_final  <<<dim3(196,BB),   dim3(256),  0, stream>>>(xz, ws, out);
  k_scatter<<<dim3(4,BB),     dim3(256),  0, stream>>>(ebev, ws, out);
}

// Round 4
// 475.165 us; speedup vs baseline: 1.1160x; 1.1160x over previous
//
#include <hip/hip_runtime.h>
#include <math.h>

// ---- problem dims ----
#define BB   16
#define SS   8
#define TKK  400
#define HH   256
#define EE   128
#define VV   50000
#define OOVV 50
#define HH2  512
#define STK  (SS*TKK)     // 3200
#define VOO  (VV+OOVV)    // 50050

// ---- workspace offsets (floats) ----
#define OFF_X     0        // B*E      = 2048
#define OFF_ST    2048     // B*H2     = 8192   s_t_hat = [h,c]
#define OFF_SD    10240    // B*H2     = 8192  (bias-inited in k_pre, atomic accum)
#define OFF_WD    18432    // B*H2     = 8192  (bias-inited in k_pre, atomic accum)
#define OFF_SCSEC 26752    // B*S      = 128
#define OFF_SCW   26880    // B*S*TK   = 51200
#define OFF_CT    78080    // B*H2     = 8192  (zeroed in k_pre, atomic accum)
#define OFF_OUT1  86272    // B*H      = 4096
#define OFF_PGEN  90368    // B        = 16
#define OFF_PSUM  93520    // 16*391   = 6256, layout [b][blk]
#define OFF_BT    113040   // 512*512 bf16 (512KB), layout [round][col*4 + swz(kg)][8]

// ---- output offsets (floats) ----
#define O_FD   0
#define O_H    800800
#define O_C    804896
#define O_CT   808992
#define O_ATTN 817184
#define O_PGEN 868384
#define O_COV  868400

#define NLB 391            // logits blocks (128 cols each)
#define GEMM_NB 800

typedef __attribute__((ext_vector_type(8))) short bf16x8;
typedef __attribute__((ext_vector_type(4))) float f32x4;

__device__ __forceinline__ float sigm(float x){ return 1.0f/(1.0f+expf(-x)); }

__device__ __forceinline__ unsigned short f2b(float f){
  unsigned int u = __float_as_uint(f);
  unsigned int r = (u + 0x7fffu + ((u >> 16) & 1u)) >> 16;
  return (unsigned short)r;
}

// fast tanh: (e^2x - 1) * rcp(e^2x + 1), clamped.  abs err ~2e-7.
__device__ __forceinline__ float tanhfast(float x){
  float cx = fminf(9.0f, fmaxf(-9.0f, x));
  float t = __expf(2.0f*cx);
  return (t - 1.0f) * __builtin_amdgcn_rcpf(t + 1.0f);
}

__device__ __forceinline__ float wave_sum(float v){
  #pragma unroll
  for(int o=32;o>0;o>>=1) v += __shfl_xor(v,o);
  return v;
}
__device__ __forceinline__ float wave_max(float v){
  #pragma unroll
  for(int o=32;o>0;o>>=1) v = fmaxf(v,__shfl_xor(v,o));
  return v;
}

// async global->LDS, 16B per lane. LDS dest = wave-uniform base + lane*16.
__device__ __forceinline__ void glds16(const void* g, void* l){
  __builtin_amdgcn_global_load_lds((const __attribute__((address_space(1))) void*)g,
                                   (__attribute__((address_space(3))) void*)l, 16, 0, 0);
}

__device__ __forceinline__ bf16x8 cvt8(float4 a, float4 b){
  union{ bf16x8 v; unsigned short u[8]; } t;
  t.u[0]=f2b(a.x); t.u[1]=f2b(a.y); t.u[2]=f2b(a.z); t.u[3]=f2b(a.w);
  t.u[4]=f2b(b.x); t.u[5]=f2b(b.y); t.u[6]=f2b(b.z); t.u[7]=f2b(b.w);
  return t.v;
}

// ------------------------------------------------------------------
// k_pre: blocks 0..63  transpose Whw -> Btg bf16 (pre-swizzled round images)
//        blocks 64..79 x = [c_t_1, emb[y]] @ W_xc + b_xc
//        block  80     zero CT; init SD/WD with biases (k_proj accumulates)
// grid 81 x 256
__global__ void k_pre(const float* __restrict__ Whw, unsigned short* __restrict__ Btg,
                      const int* __restrict__ y, const float* __restrict__ ct1,
                      const float* __restrict__ emb, const float* __restrict__ Wxc,
                      const float* __restrict__ bxc, const float* __restrict__ bdsec,
                      const float* __restrict__ bdw, float* __restrict__ ws){
  __shared__ float sm[10440];
  int bi = blockIdx.x, tid = threadIdx.x;
  if(bi < 64){
    int n0 = (bi & 7)*64, k0 = (bi >> 3)*64;
    int tx = tid & 63, ty = tid >> 6;  // ty 0..3
    #pragma unroll
    for(int it=0; it<16; it++){
      int kk = it*4 + ty;
      sm[kk*65 + tx] = Whw[(size_t)(k0+kk)*HH2 + n0 + tx];
    }
    __syncthreads();
    #pragma unroll
    for(int it=0; it<2; it++){
      int kgl = it*4 + ty;            // 0..7
      int kgG = (k0 >> 3) + kgl;
      int rnd = kgG >> 2, kg = kgG & 3;
      int col = n0 + tx;
      union{ bf16x8 v; unsigned short u[8]; } t;
      #pragma unroll
      for(int j=0;j<8;j++) t.u[j] = f2b(sm[(kgl*8+j)*65 + tx]);
      *(bf16x8*)&Btg[(size_t)rnd*16384 + (size_t)(col*4 + (kg ^ ((col>>1)&3)))*8] = t.v;
    }
  } else if(bi < 80){
    float* cat = sm;                  // [b][640]
    float* red = sm + 10240;          // 128
    for(int f=tid; f<BB*640; f+=256){
      int b = f/640, r = f - b*640;
      cat[f] = (r < HH2) ? ct1[b*HH2 + r] : emb[(size_t)y[b]*EE + (r-HH2)];
    }
    __syncthreads();
    int c = (bi-64)*8 + (tid & 7);
    int b = (tid >> 3) & 15;
    int kh = tid >> 7;                // 0..1
    float acc = 0.0f;
    const float* a = &cat[b*640];
    for(int k=kh*320; k<kh*320+320; k++) acc += a[k]*Wxc[k*EE + c];
    if(kh==1) red[b*8 + (tid&7)] = acc;
    __syncthreads();
    if(kh==0) ws[OFF_X + b*EE + c] = acc + red[b*8 + (tid&7)] + bxc[c];
  } else {
    for(int f=tid; f<BB*HH2; f+=256){
      int c = f & (HH2-1);
      ws[OFF_CT + f] = 0.0f;
      ws[OFF_SD + f] = bdsec[c];
      ws[OFF_WD + f] = bdw[c];
    }
  }
}

// ------------------------------------------------------------------
// fused LSTM.  grid 64 x 256: block = 16 j-cols x 4 b, ksplit 4
__global__ void k_lstm(const float* __restrict__ h0, const float* __restrict__ c0,
                       const float* __restrict__ Wih, const float* __restrict__ bih,
                       const float* __restrict__ Whh, const float* __restrict__ bhh,
                       float* __restrict__ ws, float* __restrict__ out){
  __shared__ float xh[4*384];
  __shared__ float red[3*64*4];
  int tid = threadIdx.x;
  int jc = (blockIdx.x & 15)*16, bc = (blockIdx.x >> 4)*4;
  for(int f=tid; f<4*384; f+=256){
    int bl = f/384, r = f - bl*384;
    xh[f] = (r < EE) ? ws[OFF_X + (bc+bl)*EE + r] : h0[(bc+bl)*HH + (r-EE)];
  }
  __syncthreads();
  int jl = tid & 15, bl = (tid >> 4) & 3, kq = tid >> 6;
  int j = jc + jl, b = bc + bl;
  float a0=0.f, a1=0.f, a2=0.f, a3=0.f;
  const float* a = &xh[bl*384];
  for(int k=kq*96; k<kq*96+96; k++){
    float v = a[k];
    const float* w = (k < EE) ? &Wih[k*4*HH + j] : &Whh[(k-EE)*4*HH + j];
    a0 += v*w[0]; a1 += v*w[HH]; a2 += v*w[2*HH]; a3 += v*w[3*HH];
  }
  if(kq){
    float* r = &red[((kq-1)*64 + bl*16 + jl)*4];
    r[0]=a0; r[1]=a1; r[2]=a2; r[3]=a3;
  }
  __syncthreads();
  if(kq==0){
    #pragma unroll
    for(int p=0;p<3;p++){
      const float* r = &red[(p*64 + bl*16 + jl)*4];
      a0+=r[0]; a1+=r[1]; a2+=r[2]; a3+=r[3];
    }
    a0 += bih[j] + bhh[j];
    a1 += bih[j+HH] + bhh[j+HH];
    a2 += bih[j+2*HH] + bhh[j+2*HH];
    a3 += bih[j+3*HH] + bhh[j+3*HH];
    float c = sigm(a1)*c0[b*HH+j] + sigm(a0)*tanhf(a2);
    float h = sigm(a3)*tanhf(c);
    out[O_H + b*HH + j] = h;
    out[O_C + b*HH + j] = c;
    ws[OFF_ST + b*HH2 + j]      = h;
    ws[OFF_ST + b*HH2 + HH + j] = c;
  }
}

// ------------------------------------------------------------------
// sd/wd projections, coalesced.  grid 64 x 256.
// block = mi(2) x cb(2: 256-col half) x kq(16: 32-k chunk).
__global__ void k_proj(const float* __restrict__ Wdsec, const float* __restrict__ Wdw,
                       float* __restrict__ ws){
  __shared__ float st[BB*32];    // [b][kk]
  int tid = threadIdx.x;
  int mi = blockIdx.x >> 5;
  int cb = (blockIdx.x >> 4) & 1;
  int kq = blockIdx.x & 15;
  int k0 = kq*32;
  for(int f=tid; f<BB*32; f+=256){
    int b = f >> 5, kk = f & 31;
    st[f] = ws[OFF_ST + b*HH2 + k0 + kk];
  }
  __syncthreads();
  int c = cb*256 + tid;
  const float* Wm = (mi ? Wdw : Wdsec) + (size_t)k0*HH2 + c;
  float acc[BB];
  #pragma unroll
  for(int b=0;b<BB;b++) acc[b] = 0.0f;
  #pragma unroll 4
  for(int kk=0;kk<32;kk++){
    float wv = Wm[(size_t)kk*HH2];
    #pragma unroll
    for(int b=0;b<BB;b++) acc[b] += st[b*32 + kk]*wv;
  }
  int dst = mi ? OFF_WD : OFF_SD;
  #pragma unroll
  for(int b=0;b<BB;b++) atomicAdd(&ws[dst + b*HH2 + c], acc[b]);
}

// ------------------------------------------------------------------
// k_gemm6 blocks 0..799: 64 rows x 512 cols, K=512, BK=32.
//   Counted-vmcnt pipeline, depth-1-early A in NAMED registers (no arrays ->
//   no scratch; round-3's pa[2][4] FIFO spilled to local mem: 147MB writes).
//   - A(r+1): 4 float4 loads issued at TOP of round r, cvt at END of round r
//     in the vmcnt shadow -> ~1 full round (~2k cyc) of flight > HBM latency.
//   - B double-buffered via global_load_lds (pre-swizzled Btg); s_waitcnt
//     vmcnt(4) at end of round keeps B(r+2)'s 4 glds in flight across barriers.
//   8 waves = 2 row-groups x 4 col-groups (wave tile 32x128): B LDS read
//   replication 2x (vs 4x in the 16x256 tiling) -> LDS-pipe floor halves.
// blocks 800..927: section attention (fp32-precise) -> SCSEC.
// grid 928 x 512, 64 KB LDS -> 2 blocks/CU (16 waves).
__global__ __launch_bounds__(512, 4) void k_gemm6(
        const float* __restrict__ A, const unsigned short* __restrict__ Btg,
        const float* __restrict__ Wcw, const float* __restrict__ vw,
        const float* __restrict__ cover,
        const float* __restrict__ sec, const float* __restrict__ Whsec,
        const float* __restrict__ vsec, float* __restrict__ ws){
  // shorts: Bs0[0..16383] Bs1[16384..32767]   (64 KB)
  __shared__ __align__(16) unsigned short smem[32768];
  int tid = threadIdx.x;
  if(blockIdx.x >= GEMM_NB){
    // ---- esec: one block per (b,s) row, precise fp32 ----
    float* row = (float*)smem;            // 512 floats
    float* red = row + HH2;               // 8
    int bi = blockIdx.x - GEMM_NB;        // 0..127
    int b = bi >> 3;
    if(tid < HH2) row[tid] = sec[(size_t)bi*HH2 + tid];
    __syncthreads();
    int col = tid;                        // 0..511
    float acc = 0.0f;
    #pragma unroll 8
    for(int k=0;k<HH2;k++) acc += row[k]*Whsec[k*HH2 + col];
    float val = tanhf(acc + ws[OFF_SD + b*HH2 + col]) * vsec[col];
    val = wave_sum(val);
    if((tid&63)==0) red[tid>>6] = val;
    __syncthreads();
    if(tid==0){
      float s = 0.0f;
      #pragma unroll
      for(int i=0;i<8;i++) s += red[i];
      ws[OFF_SCSEC + bi] = s;
    }
    return;
  }
  // ---- gemm ----
  int w = tid >> 6, lane = tid & 63, m = lane & 15, q = lane >> 4;
  int mk = (m >> 1) & 3, sw = q ^ mk;    // XOR-swizzle slot for kg reads
  int rg = w >> 2, cg = w & 3;           // 2 row-groups x 4 col-groups
  int row0 = blockIdx.x * 64;
  int b = blockIdx.x / 50;               // 50 blocks per batch

  // per-lane A fragment sources: rows rg*32+m and rg*32+16+m, k-slot q
  const float* a0p = &A[(size_t)(row0 + rg*32 + m)*HH2 + q*8];
  const float* a1p = a0p + (size_t)16*HH2;

  f32x4 acc0[8], acc1[8];
  #pragma unroll
  for(int j=0;j<8;j++){ acc0[j] = (f32x4){0.f,0.f,0.f,0.f}; acc1[j] = (f32x4){0.f,0.f,0.f,0.f}; }

  float4 pa0, pa1, pa2, pa3;             // NAMED A-prefetch regs (no arrays!)
  bf16x8 af0, af1;

  #define GLDSB(rr, buf) {                                                     \
    const unsigned short* bsrc_ = Btg + (size_t)(rr)*16384;                    \
    unsigned short* ldst_ = &smem[(size_t)(buf)*16384];                        \
    _Pragma("unroll")                                                          \
    for(int i_=0;i_<4;i_++)                                                    \
      glds16(bsrc_ + i_*4096 + tid*8, ldst_ + i_*4096 + tid*8);                \
  }
  #define LOADA(rr) {                                                          \
    pa0 = *(const float4*)(a0p + (rr)*32);                                     \
    pa1 = *(const float4*)(a0p + (rr)*32 + 4);                                 \
    pa2 = *(const float4*)(a1p + (rr)*32);                                     \
    pa3 = *(const float4*)(a1p + (rr)*32 + 4);                                 \
  }

  // ---- prologue: FIFO = [B(0)x4, A(0)x4, B(1)x4] ----
  GLDSB(0, 0);
  LOADA(0);
  GLDSB(1, 1);
  asm volatile("s_waitcnt vmcnt(8)" ::: "memory");   // B(0) landed
  __builtin_amdgcn_sched_barrier(0);
  af0 = cvt8(pa0, pa1);                              // compiler waits A(0)
  af1 = cvt8(pa2, pa3);
  __builtin_amdgcn_s_barrier();                      // B(0) visible block-wide

  for(int r=0; r<16; r++){
    if(r < 15) LOADA(r+1);                           // A(r+1) early, full-round flight
    __builtin_amdgcn_s_setprio(1);
    #pragma unroll
    for(int cf=0; cf<8; cf++){
      int col = cg*128 + cf*16 + m;
      bf16x8 bv = *(const bf16x8*)&smem[(size_t)(r&1)*16384 + ((size_t)col*4 + sw)*8];
      acc0[cf] = __builtin_amdgcn_mfma_f32_16x16x32_bf16(af0, bv, acc0[cf], 0,0,0);
      acc1[cf] = __builtin_amdgcn_mfma_f32_16x16x32_bf16(af1, bv, acc1[cf], 0,0,0);
    }
    __builtin_amdgcn_s_setprio(0);
    if(r <= 13){
      asm volatile("s_waitcnt lgkmcnt(0)" ::: "memory");  // my B reads retired
      __builtin_amdgcn_sched_barrier(0);
      __builtin_amdgcn_s_barrier();                  // BAR-A: buf[r&1] free
      GLDSB(r+2, r&1);                               // B(r+2)
    }
    if(r < 15){
      if(r <= 13){ asm volatile("s_waitcnt vmcnt(4)" ::: "memory"); } // A(r+1),B(r+1) done; B(r+2) in flight
      else       { asm volatile("s_waitcnt vmcnt(0)" ::: "memory"); }
      __builtin_amdgcn_sched_barrier(0);
      af0 = cvt8(pa0, pa1);                          // A(r+1) in barrier shadow
      af1 = cvt8(pa2, pa3);
      __builtin_amdgcn_s_barrier();                  // BAR-B: B(r+1) ready
    }
  }
  #undef GLDSB
  #undef LOADA

  // ---- epilogue: fold cols with tanh into per-row sums ----
  float cov0[4], cov1[4];
  #pragma unroll
  for(int r=0;r<4;r++){
    cov0[r] = cover[row0 + rg*32 + q*4 + r];
    cov1[r] = cover[row0 + rg*32 + 16 + q*4 + r];
  }
  float rs0[4] = {0,0,0,0}, rs1[4] = {0,0,0,0};
  #pragma unroll
  for(int j=0;j<8;j++){
    int col = cg*128 + j*16 + m;
    float wdv = ws[OFF_WD + b*HH2 + col];
    float wcv = Wcw[col], vwv = vw[col];
    #pragma unroll
    for(int r=0;r<4;r++){
      rs0[r] += tanhfast(acc0[j][r] + wdv + cov0[r]*wcv) * vwv;
      rs1[r] += tanhfast(acc1[j][r] + wdv + cov1[r]*wcv) * vwv;
    }
  }
  __syncthreads();                 // all waves past K-loop; smem reusable
  float* rbuf = (float*)smem;      // [cg][64 rows] = 256 floats
  #pragma unroll
  for(int r=0;r<4;r++){
    float v = rs0[r];
    v += __shfl_xor(v,1,16); v += __shfl_xor(v,2,16);
    v += __shfl_xor(v,4,16); v += __shfl_xor(v,8,16);
    if(m==0) rbuf[cg*64 + rg*32 + q*4 + r] = v;
    float u = rs1[r];
    u += __shfl_xor(u,1,16); u += __shfl_xor(u,2,16);
    u += __shfl_xor(u,4,16); u += __shfl_xor(u,8,16);
    if(m==0) rbuf[cg*64 + rg*32 + 16 + q*4 + r] = u;
  }
  __syncthreads();
  if(tid < 64)
    ws[OFF_SCW + row0 + tid] = rbuf[tid] + rbuf[64+tid] + rbuf[128+tid] + rbuf[192+tid];
}

// ------------------------------------------------------------------
// beta (inline) + attn softmax + mask + renorm + coverage out.  grid 16 x 1024
__global__ void k_attn(const float* __restrict__ mask, const float* __restrict__ cover,
                       float* __restrict__ ws, float* __restrict__ out){
  int b = blockIdx.x, tid = threadIdx.x;
  __shared__ float vals[STK];
  __shared__ float redm[16], reds[16];
  __shared__ float sc[SS];
  if(tid < SS) sc[tid] = ws[OFF_SCSEC + b*SS + tid];
  __syncthreads();
  float bm = -1e30f;
  #pragma unroll
  for(int s=0;s<SS;s++) bm = fmaxf(bm, sc[s]);
  float be[SS]; float bsum = 0.0f;
  #pragma unroll
  for(int s=0;s<SS;s++){ be[s] = expf(sc[s]-bm); bsum += be[s]; }
  #pragma unroll
  for(int s=0;s<SS;s++) be[s] /= bsum;
  int lane = tid & 63, w = tid >> 6;
  float m = -1e30f;
  for(int j=tid;j<STK;j+=1024){
    float v = be[j/TKK] * ws[OFF_SCW + b*STK + j];
    vals[j] = v; m = fmaxf(m, v);
  }
  m = wave_max(m);
  if(lane==0) redm[w] = m;
  __syncthreads();
  if(tid < 16){
    float t = redm[tid];
    #pragma unroll
    for(int o=8;o>0;o>>=1) t = fmaxf(t, __shfl_xor(t,o,16));
    if(tid==0) redm[0] = t;
  }
  __syncthreads();
  m = redm[0];
  float ssum = 0.0f;
  for(int j=tid;j<STK;j+=1024){
    float e = expf(vals[j]-m) * mask[b*STK + j];
    vals[j] = e; ssum += e;
  }
  ssum = wave_sum(ssum);
  if(lane==0) reds[w] = ssum;
  __syncthreads();
  if(tid < 16){
    float t = reds[tid];
    #pragma unroll
    for(int o=8;o>0;o>>=1) t += __shfl_xor(t,o,16);
    if(tid==0) reds[0] = t;
  }
  __syncthreads();
  float inv = 1.0f/reds[0];
  for(int j=tid;j<STK;j+=1024){
    float a = vals[j]*inv;
    out[O_ATTN + b*STK + j] = a;
    out[O_COV  + b*STK + j] = cover[b*STK + j] + a;
  }
}

// ------------------------------------------------------------------
// c_t = attn @ enc.  grid (50,16) x 256.  float4-coalesced, LDS pair-reduce,
// one atomic per col per block.
__global__ void k_ct(const float* __restrict__ enc, const float* __restrict__ out,
                     float* __restrict__ ws){
  int b = blockIdx.y, tid = threadIdx.x;
  __shared__ float a[64];
  __shared__ float part[512];
  int t0 = blockIdx.x*64;
  if(tid<64) a[tid] = out[O_ATTN + b*STK + t0 + tid];
  __syncthreads();
  int c4 = tid & 127, rh = tid >> 7;       // col-quad, row-half
  const float4* e4 = (const float4*)enc;
  size_t base = ((size_t)(b*STK + t0 + rh*32))*128 + c4;
  float4 acc = {0.f,0.f,0.f,0.f};
  #pragma unroll 8
  for(int rr=0; rr<32; rr++){
    float4 v = e4[base + (size_t)rr*128];
    float av = a[rh*32 + rr];
    acc.x += av*v.x; acc.y += av*v.y; acc.z += av*v.z; acc.w += av*v.w;
  }
  if(rh) *(float4*)&part[c4*4] = acc;
  __syncthreads();
  if(!rh){
    float4 o = *(const float4*)&part[c4*4];
    atomicAdd(&ws[OFF_CT + b*HH2 + c4*4 + 0], acc.x + o.x);
    atomicAdd(&ws[OFF_CT + b*HH2 + c4*4 + 1], acc.y + o.y);
    atomicAdd(&ws[OFF_CT + b*HH2 + c4*4 + 2], acc.z + o.z);
    atomicAdd(&ws[OFF_CT + b*HH2 + c4*4 + 3], acc.w + o.w);
  }
}

// ------------------------------------------------------------------
// out1: grid 65 x 256. blocks 0..63: 4 cols x 16 b, ksplit 4.
// block 64: p_gen + c_t output copy.
__global__ void k_out1(const float* __restrict__ Wp, const float* __restrict__ bp,
                       const float* __restrict__ Wo1, const float* __restrict__ bo1,
                       float* __restrict__ ws, float* __restrict__ out){
  __shared__ float cat[BB*768];   // 48 KB
  __shared__ float red[3*64];
  int tid = threadIdx.x;
  if(blockIdx.x == 64){
    int w = tid >> 6, lane = tid & 63;
    #pragma unroll
    for(int i=0;i<4;i++){
      int b = w*4 + i;
      float p = 0.0f;
      for(int k=lane;k<4*HH+EE;k+=64){
        float val = (k < HH2) ? ws[OFF_CT + b*HH2 + k]
                  : (k < 4*HH) ? ws[OFF_ST + b*HH2 + (k-HH2)]
                  : ws[OFF_X + b*EE + (k-4*HH)];
        p += val * Wp[k];
      }
      p = wave_sum(p);
      if(lane==0){
        float pg = sigm(p + bp[0]);
        ws[OFF_PGEN + b] = pg;
        out[O_PGEN + b]  = pg;
      }
    }
    for(int f=tid; f<BB*HH2; f+=256) out[O_CT + f] = ws[OFF_CT + f];
    return;
  }
  for(int f=tid; f<BB*768; f+=256){
    int b = f/768, r = f - b*768;
    cat[f] = (r < HH) ? ws[OFF_ST + b*HH2 + r] : ws[OFF_CT + b*HH2 + (r-HH)];
  }
  __syncthreads();
  int cl = tid & 3, bl = (tid >> 2) & 15, kq = tid >> 6;
  int c = blockIdx.x*4 + cl;
  float acc = 0.0f;
  const float* a = &cat[bl*768];
  for(int k=kq*192; k<kq*192+192; k++) acc += a[k]*Wo1[k*HH + c];
  if(kq) red[(kq-1)*64 + bl*4 + cl] = acc;
  __syncthreads();
  if(kq==0){
    acc += red[bl*4+cl] + red[64 + bl*4+cl] + red[128 + bl*4+cl];
    ws[OFF_OUT1 + bl*HH + c] = acc + bo1[c];
  }
}

// ------------------------------------------------------------------
// logits -> exp + per-block PSUM.  grid 391 x 256.
// Block = 128 cols x 16 b.  float4 W2 loads.
__global__ void k_logits(const float* __restrict__ W2, const float* __restrict__ b2,
                         float* __restrict__ ws, float* __restrict__ out){
  int tid = threadIdx.x;
  __shared__ float o1[BB*HH];        // 16 KB
  for(int i=tid;i<BB*HH/4;i+=256)
    ((float4*)o1)[i] = ((const float4*)&ws[OFF_OUT1])[i];
  __syncthreads();
  int cl = tid & 31, bq = tid >> 5;
  int c4 = blockIdx.x*128 + cl*4;
  bool ok = c4 < VV;
  int b0 = bq*2, b1 = b0+1;
  float4 acc0 = {0.f,0.f,0.f,0.f}, acc1 = {0.f,0.f,0.f,0.f};
  if(ok){
    const float* oa = &o1[b0*HH];
    const float* ob = &o1[b1*HH];
    #pragma unroll 4
    for(int k=0;k<HH;k++){
      float4 wv = *(const float4*)&W2[(size_t)k*VV + c4];
      float xa = oa[k], xb = ob[k];
      acc0.x += xa*wv.x; acc0.y += xa*wv.y; acc0.z += xa*wv.z; acc0.w += xa*wv.w;
      acc1.x += xb*wv.x; acc1.y += xb*wv.y; acc1.z += xb*wv.z; acc1.w += xb*wv.w;
    }
  }
  float bv[4] = {0,0,0,0};
  if(ok){ float4 t = *(const float4*)&b2[c4]; bv[0]=t.x; bv[1]=t.y; bv[2]=t.z; bv[3]=t.w; }
  float a0[4] = {acc0.x, acc0.y, acc0.z, acc0.w};
  float a1[4] = {acc1.x, acc1.y, acc1.z, acc1.w};
  float s0 = 0.0f, s1 = 0.0f;
  #pragma unroll
  for(int j=0;j<4;j++){
    float e0 = ok ? expf(a0[j]+bv[j]) : 0.0f;
    float e1 = ok ? expf(a1[j]+bv[j]) : 0.0f;
    if(ok){
      out[(size_t)b0*VOO + c4 + j] = e0;
      out[(size_t)b1*VOO + c4 + j] = e1;
    }
    s0 += e0; s1 += e1;
  }
  #pragma unroll
  for(int o=1;o<32;o<<=1){ s0 += __shfl_xor(s0,o,32); s1 += __shfl_xor(s1,o,32); }
  if(cl==0){
    ws[OFF_PSUM + b0*NLB + blockIdx.x] = s0;
    ws[OFF_PSUM + b1*NLB + blockIdx.x] = s1;
  }
}

// ------------------------------------------------------------------
// final_dist = p_gen * e / sum (v<V), extra_zeros tail.  grid (196,16) x 256
__global__ void k_final(const float* __restrict__ xz, float* __restrict__ ws,
                        float* __restrict__ out){
  int b = blockIdx.y;
  int v = blockIdx.x*256 + threadIdx.x;
  __shared__ float red[4];
  int lane = threadIdx.x & 63, w = threadIdx.x >> 6;
  float p = 0.0f;
  for(int i=threadIdx.x;i<NLB;i+=256) p += ws[OFF_PSUM + b*NLB + i];
  p = wave_sum(p);
  if(lane==0) red[w] = p;
  __syncthreads();
  float s = red[0]+red[1]+red[2]+red[3];
  float pg = ws[OFF_PGEN + b];
  if(v < VV)       out[(size_t)b*VOO + v] = pg * out[(size_t)b*VOO + v] / s;
  else if(v < VOO) out[(size_t)b*VOO + v] = xz[b*OOVV + (v-VV)];
}

// ------------------------------------------------------------------
// scatter-add (1-p_gen)*attn at extend-vocab indices.  grid (4,16) x 256
__global__ void k_scatter(const int* __restrict__ ebev, float* __restrict__ ws,
                          float* __restrict__ out){
  int b = blockIdx.y;
  float r = 1.0f - ws[OFF_PGEN + b];
  for(int j=blockIdx.x*256+threadIdx.x;j<STK;j+=1024){
    int idx = ebev[b*STK + j];
    atomicAdd(&out[(size_t)b*VOO + idx], r*out[O_ATTN + b*STK + j]);
  }
}

extern "C" void kernel_launch(void* const* d_in, const int* in_sizes, int n_in,
                              void* d_out, int out_size, void* d_ws, size_t ws_size,
                              hipStream_t stream){
  const int*   y     = (const int*)  d_in[0];
  const float* h0    = (const float*)d_in[1];
  const float* c0    = (const float*)d_in[2];
  const float* enc   = (const float*)d_in[3];
  const float* sec   = (const float*)d_in[4];
  const float* mask  = (const float*)d_in[5];
  const float* ct1   = (const float*)d_in[6];
  const float* xz    = (const float*)d_in[7];
  const int*   ebev  = (const int*)  d_in[8];
  const float* cover = (const float*)d_in[9];
  /* d_in[10] = gamma (unused by reference) */
  const float* emb   = (const float*)d_in[11];
  const float* Wxc   = (const float*)d_in[12];
  const float* bxc   = (const float*)d_in[13];
  const float* Wih   = (const float*)d_in[14];
  const float* bih   = (const float*)d_in[15];
  const float* Whh   = (const float*)d_in[16];
  const float* bhh   = (const float*)d_in[17];
  const float* Whsec = (const float*)d_in[18];
  const float* Wdsec = (const float*)d_in[19];
  const float* bdsec = (const float*)d_in[20];
  const float* vsec  = (const float*)d_in[21];
  const float* Whw   = (const float*)d_in[22];
  const float* Wcw   = (const float*)d_in[23];
  const float* Wdw   = (const float*)d_in[24];
  const float* bdw   = (const float*)d_in[25];
  const float* vw    = (const float*)d_in[26];
  const float* Wp    = (const float*)d_in[27];
  const float* bp    = (const float*)d_in[28];
  const float* Wo1   = (const float*)d_in[29];
  const float* bo1   = (const float*)d_in[30];
  const float* Wo2   = (const float*)d_in[31];
  const float* bo2   = (const float*)d_in[32];
  float* out = (float*)d_out;
  float* ws  = (float*)d_ws;
  unsigned short* Btg = (unsigned short*)(ws + OFF_BT);

  k_pre    <<<dim3(81),       dim3(256),  0, stream>>>(Whw, Btg, y, ct1, emb, Wxc, bxc, bdsec, bdw, ws);
  k_lstm   <<<dim3(64),       dim3(256),  0, stream>>>(h0, c0, Wih, bih, Whh, bhh, ws, out);
  k_proj   <<<dim3(64),       dim3(256),  0, stream>>>(Wdsec, Wdw, ws);
  k_gemm6  <<<dim3(928),      dim3(512),  0, stream>>>(enc, Btg, Wcw, vw, cover, sec, Whsec, vsec, ws);
  k_attn   <<<dim3(BB),       dim3(1024), 0, stream>>>(mask, cover, ws, out);
  k_ct     <<<dim3(50,BB),    dim3(256),  0, stream>>>(enc, out, ws);
  k_out1   <<<dim3(65),       dim3(256),  0, stream>>>(Wp, bp, Wo1, bo1, ws, out);
  k_logits <<<dim3(NLB),      dim3(256),  0, stream>>>(Wo2, bo2, ws, out);
  k_final  <<<dim3(196,BB),   dim3(256),  0, stream>>>(xz, ws, out);
  k_scatter<<<dim3(4,BB),     dim3(256),  0, stream>>>(ebev, ws, out);
}